// Round 12
// baseline (233.993 us; speedup 1.0000x reference)
//
#include <hip/hip_runtime.h>
#include <math.h>

// SGC: K=2 hops of D^-1/2 (A+I) D^-1/2, then x@W+b, then log_softmax.
// N=100000, D=64, C=40, E=1600000.
//
// R20: revert R19's sort+xw fusion (unified regalloc compiled the xw path
// at 32 VGPR -> acc[40] spilled to scratch -> 46us vs 10+10 separate).
// Keep R19's spmm launch_bounds(256,8) + single accumulator bank and
// bin_edges EPT=8 (occupancy arithmetic unchanged).
//
// Carried: XW-first pipeline (R16-R18), init_kernel instead of memsets
// (R18), 5-lane x uint4 gathers (12 rows/wave), pinfo, guard region,
// bitonic row sort, degree-grouped scheduling, pk_add accumulate.

#define D_FEAT 64
#define NCLS 40
#define NDW 20          // dwords per 40-bf16 row
#define NV4 5           // uint4 per row
#define BROWS 512       // rows per bucket
#define BROWS_LOG 9
#define BINCAP 10240    // per-bucket edge capacity (mean 8192, sd ~90)
#define CSRCAP 12288    // per-bucket csr capacity (max padded 11776 + 512 guard)
#define EPT 8           // edges per thread in bin_edges (782 blocks)

typedef float v2f __attribute__((ext_vector_type(2)));

__device__ __forceinline__ unsigned pack_bf16_2(float lo, float hi) {
    unsigned ulo = __float_as_uint(lo);
    unsigned uhi = __float_as_uint(hi);
    ulo = (ulo + 0x7fffu + ((ulo >> 16) & 1u)) >> 16;           // RNE
    uhi = (uhi + 0x7fffu + ((uhi >> 16) & 1u)) & 0xffff0000u;   // RNE
    return uhi | ulo;
}

// packed-accumulate one dword (2 bf16 features) into a float2 accumulator
__device__ __forceinline__ void acc2p(unsigned u, v2f& a) {
    v2f v;
    v.x = __uint_as_float(u << 16);
    v.y = __uint_as_float(u & 0xffff0000u);
    a += v;   // <2 x float> fadd -> v_pk_add_f32
}

// Zero bucket_cursor + the dummy row n of y0/y1 (guard-gather target).
__global__ void init_kernel(int* __restrict__ bucket_cursor,
                            unsigned* __restrict__ y0, unsigned* __restrict__ y1,
                            int n, int nb) {
    int i = threadIdx.x;
    if (i < nb) bucket_cursor[i] = 0;
    if (i < NDW) {
        y0[(size_t)n * NDW + i] = 0u;
        y1[(size_t)n * NDW + i] = 0u;
    }
}

// Bin edges into per-bucket regions. Packed entry: (row&511)<<17 | col.
// (Requires n <= 131072 so col fits 17 bits; n = 100000 here.)
__global__ __launch_bounds__(256) void bin_edges_kernel(const int* __restrict__ rows,
                                                        const int* __restrict__ cols,
                                                        int* __restrict__ bucket_cursor,
                                                        unsigned* __restrict__ bins,
                                                        int e, int nb) {
    __shared__ int cnt[512];
    for (int i = threadIdx.x; i < nb; i += 256) cnt[i] = 0;
    __syncthreads();
    int base = blockIdx.x * (256 * EPT) + threadIdx.x;
    int rr[EPT], cc[EPT];
#pragma unroll
    for (int k = 0; k < EPT; k++) {
        int idx = base + k * 256;
        if (idx < e) { rr[k] = rows[idx]; cc[k] = cols[idx]; }
        else { rr[k] = -1; cc[k] = 0; }
    }
#pragma unroll
    for (int k = 0; k < EPT; k++)
        if (rr[k] >= 0) atomicAdd(&cnt[rr[k] >> BROWS_LOG], 1);
    __syncthreads();
    for (int i = threadIdx.x; i < nb; i += 256) {
        int c = cnt[i];
        cnt[i] = (c > 0) ? atomicAdd(&bucket_cursor[i], c) : 0;  // global base
    }
    __syncthreads();
#pragma unroll
    for (int k = 0; k < EPT; k++) {
        if (rr[k] >= 0) {
            int b = rr[k] >> BROWS_LOG;
            int pos = atomicAdd(&cnt[b], 1);  // absolute pos within bucket
            bins[(size_t)b * BINCAP + pos] =
                ((unsigned)(rr[k] & (BROWS - 1)) << 17) | (unsigned)cc[k];
        }
    }
}

// One 512-thread block per bucket, all staged in LDS. Emits UNSORTED,
// dummy-padded CSR + 512-entry guard (value n) + row_info + dis + pinfo
// (degree-grouped wave schedule, packed with csr base/len/row/dis).
__global__ __launch_bounds__(512) void build_csr_kernel(const unsigned* __restrict__ bins,
                                                        const int* __restrict__ bucket_cursor,
                                                        int* __restrict__ csr_col,
                                                        uint2* __restrict__ row_info,
                                                        float* __restrict__ dis,
                                                        uint4* __restrict__ pinfo, int n) {
    __shared__ int cnt[512];
    __shared__ int sm[512];
    __shared__ int cur[512];
    __shared__ int lcsr[CSRCAP];  // 48 KB; total static LDS = 54 KB
    int b = blockIdx.x;
    int tid = threadIdx.x;
    int m = bucket_cursor[b];
    cnt[tid] = 0;
    __syncthreads();
    const unsigned* bp = bins + (size_t)b * BINCAP;
    for (int i = tid; i < m; i += 512) atomicAdd(&cnt[bp[i] >> 17], 1);
    __syncthreads();
    int c = cnt[tid];
    int padded = (c + 3) & ~3;
    int r = b * BROWS + tid;
    float dv = rsqrtf(1.0f + (float)c);
    if (r < n) dis[r] = dv;
    sm[tid] = padded;
    __syncthreads();
    for (int off = 1; off < 512; off <<= 1) {
        int t = (tid >= off) ? sm[tid - off] : 0;
        __syncthreads();
        sm[tid] += t;
        __syncthreads();
    }
    int off0 = sm[tid] - padded;  // exclusive scan
    cur[tid] = off0;
    if (r < n) row_info[r] = make_uint2((unsigned)(b * CSRCAP + off0), (unsigned)padded);
    __syncthreads();
    for (int i = tid; i < m; i += 512) {
        unsigned u = bp[i];
        int pos = atomicAdd(&cur[u >> 17], 1);
        lcsr[pos] = (int)(u & 0x1FFFFu);
    }
    __syncthreads();
    // dummy-pad own row's tail (pad slots gather zero row n in SpMM)
    if (r < n) {
        for (int j = c; j < padded; j++) lcsr[off0 + j] = n;
    }
    __syncthreads();
    int tot = sm[511];  // total padded slots (multiple of 4)
    int4* cp4 = (int4*)(csr_col + (size_t)b * CSRCAP);
    const int4* l4 = (const int4*)lcsr;
    for (int i = tid; i < (tot >> 2); i += 512) cp4[i] = l4[i];
    // guard region: SpMM reads csr up to ~256 ints past a row's end; fill 512
    // entries of value n past tot (row n of y0/y1 is zeros).
    {
        int g = tot + tid;
        if (g < CSRCAP) csr_col[(size_t)b * CSRCAP + g] = n;
    }

    // ---- degree-grouped pinfo: counting sort of bucket rows by padded len --
    // (rank order within a bin is nondeterministic, but output is per-row
    //  independent of wave assignment -> bit-identical results.)
    __syncthreads();
    if (tid < 64) cnt[tid] = 0;
    __syncthreads();
    int bin = min(padded >> 2, 63);
    if (r < n) atomicAdd(&cnt[bin], 1);
    __syncthreads();
    if (tid < 64) sm[tid] = cnt[tid];
    __syncthreads();
    for (int off = 1; off < 64; off <<= 1) {
        int t = (tid >= off && tid < 64) ? sm[tid - off] : 0;
        __syncthreads();
        if (tid < 64) sm[tid] += t;
        __syncthreads();
    }
    if (tid < 64) cur[tid] = sm[tid] - cnt[tid];  // exclusive bin base
    __syncthreads();
    if (r < n) {
        int rank = atomicAdd(&cur[bin], 1);
        pinfo[b * BROWS + rank] = make_uint4((unsigned)(b * CSRCAP + off0),
                                             (unsigned)padded, (unsigned)r,
                                             __float_as_uint(dv));
    } else {
        // tid >= valid-count exactly when r >= n
        pinfo[b * BROWS + tid] = make_uint4(0u, 0u, 0xFFFFFFFFu, 0u);
    }
}

// Sort each padded CSR row ascending (canonical multiset order -> output is
// bit-identical across replays regardless of scatter order). One half-wave
// (32 lanes) per row via bitonic network; rows with padded>32 (P ~ 1e-3) use
// a 64-lane pass; padded>64 (unreachable for this data) falls back serial.
__global__ __launch_bounds__(256) void sort_rows_kernel(int* __restrict__ csr_col,
                                                        const uint2* __restrict__ row_info,
                                                        int n) {
    int wid = (int)((blockIdx.x * blockDim.x + threadIdx.x) >> 6);
    int lane = threadIdx.x & 63;
    int r0 = wid * 2, r1 = r0 + 1;
    if (r0 >= n) return;
    uint2 i0 = row_info[r0];
    uint2 i1 = (r1 < n) ? row_info[r1] : make_uint2(0u, 0u);
    int p0 = (int)i0.y, p1 = (int)i1.y;
    if (p0 <= 32 && p1 <= 32) {
        int half = lane >> 5, hl = lane & 31;
        int base = half ? (int)i1.x : (int)i0.x;
        int pad  = half ? p1 : p0;
        int key = (hl < pad) ? csr_col[base + hl] : 0x7fffffff;
#pragma unroll
        for (int k = 2; k <= 32; k <<= 1) {
#pragma unroll
            for (int j = k >> 1; j > 0; j >>= 1) {
                int other = __shfl_xor(key, j, 64);  // j<32: stays in half
                bool takeMin = (((hl & j) == 0) == ((hl & k) == 0));
                int mn = min(key, other), mx = max(key, other);
                key = takeMin ? mn : mx;
            }
        }
        if (hl < pad) csr_col[base + hl] = key;
    } else {
        for (int t = 0; t < 2; t++) {
            int base = t ? (int)i1.x : (int)i0.x;
            int pad  = t ? p1 : p0;
            if (pad == 0) continue;
            if (pad <= 64) {
                int key = (lane < pad) ? csr_col[base + lane] : 0x7fffffff;
#pragma unroll
                for (int k = 2; k <= 64; k <<= 1) {
#pragma unroll
                    for (int j = k >> 1; j > 0; j >>= 1) {
                        int other = __shfl_xor(key, j, 64);
                        bool takeMin = (((lane & j) == 0) == ((lane & k) == 0));
                        int mn = min(key, other), mx = max(key, other);
                        key = takeMin ? mn : mx;
                    }
                }
                if (lane < pad) csr_col[base + lane] = key;
            } else if (lane == 0) {
                for (int i2 = 1; i2 < pad; i2++) {
                    int kk = csr_col[base + i2];
                    int j2 = i2 - 1;
                    while (j2 >= 0 && csr_col[base + j2] > kk) {
                        csr_col[base + j2 + 1] = csr_col[base + j2]; j2--;
                    }
                    csr_col[base + j2 + 1] = kk;
                }
            }
        }
    }
}

// Y0[r,:] = bf16( dis[r] * (X[r,:] @ W) ), 40 bf16 packed into 20 dwords.
// 1 row per thread; W read via wave-uniform global addresses (scalar K$
// loads -- no LDS, no barrier); X streamed float4; uint4 stores.
__global__ __launch_bounds__(256) void xw_kernel(const float* __restrict__ x,
                                                 const float* __restrict__ W,
                                                 const float* __restrict__ dis,
                                                 unsigned* __restrict__ y0, int n) {
    int r = blockIdx.x * 256 + threadIdx.x;
    if (r >= n) return;
    float acc[NCLS];
#pragma unroll
    for (int c = 0; c < NCLS; c++) acc[c] = 0.f;
    const float4* xp = (const float4*)(x + (size_t)r * D_FEAT);
#pragma unroll 4
    for (int dg = 0; dg < 16; dg++) {
        float4 xa = xp[dg];
#pragma unroll
        for (int j = 0; j < 4; j++) {
            float a = (j == 0) ? xa.x : (j == 1) ? xa.y : (j == 2) ? xa.z : xa.w;
            int d = dg * 4 + j;
#pragma unroll
            for (int c4 = 0; c4 < 10; c4++) {
                float4 wv = *(const float4*)(W + d * NCLS + c4 * 4);  // uniform
                acc[c4 * 4 + 0] += a * wv.x;
                acc[c4 * 4 + 1] += a * wv.y;
                acc[c4 * 4 + 2] += a * wv.z;
                acc[c4 * 4 + 3] += a * wv.w;
            }
        }
    }
    float s = dis[r];
    uint4* p = (uint4*)(y0 + (size_t)r * NDW);
#pragma unroll
    for (int q = 0; q < NV4; q++) {
        uint4 o;
        o.x = pack_bf16_2(s * acc[8 * q + 0], s * acc[8 * q + 1]);
        o.y = pack_bf16_2(s * acc[8 * q + 2], s * acc[8 * q + 3]);
        o.z = pack_bf16_2(s * acc[8 * q + 4], s * acc[8 * q + 5]);
        o.w = pack_bf16_2(s * acc[8 * q + 6], s * acc[8 * q + 7]);
        p[q] = o;
    }
}

// One gather iteration: 8 UNCONDITIONAL uint4 row-gathers (5 lanes per row,
// 12 rows per wave) + sched_barrier, then accumulates predicated per 4-slot
// group. Single accumulator bank (h0..h3): 8-deep pk_add chain = ~32cy,
// covered by 8-wave/SIMD TLP; keeps peak VGPR ~60 for launch_bounds(256,8).
#define ACC1(u) acc2p(u.x, h0); acc2p(u.y, h1); acc2p(u.z, h2); acc2p(u.w, h3);
#define GATHER8(cp, xs4, gl, base, len)                                     \
    uint4 cv0 = cp[(base >> 2)], cv1 = cp[(base >> 2) + 1];                 \
    uint4 u0 = xs4[cv0.x * NV4 + gl], u1 = xs4[cv0.y * NV4 + gl];           \
    uint4 u2 = xs4[cv0.z * NV4 + gl], u3 = xs4[cv0.w * NV4 + gl];           \
    uint4 u4 = xs4[cv1.x * NV4 + gl], u5 = xs4[cv1.y * NV4 + gl];           \
    uint4 u6 = xs4[cv1.z * NV4 + gl], u7 = xs4[cv1.w * NV4 + gl];           \
    __builtin_amdgcn_sched_barrier(0);                                      \
    if (base < len)     { ACC1(u0) ACC1(u1) ACC1(u2) ACC1(u3) }             \
    if (base + 4 < len) { ACC1(u4) ACC1(u5) ACC1(u6) ACC1(u7) }

// Hop 1: y1[r,:] = bf16( dis[r]^2 * ( y0[r,:] + sum_c y0[c,:] ) ).
// Wave: 12 rows from pinfo[12w..12w+11]; 5-lane group per row; lane gl holds
// feats 8gl..8gl+7 (uint4). Lanes 60..63 idle. Grid = one resident round at
// 8 waves/SIMD.
__global__ __launch_bounds__(256, 8) void spmm_hop1_kernel(const uint4* __restrict__ xs_in,
                                                           uint4* __restrict__ xs_out,
                                                           const uint4* __restrict__ pinfo,
                                                           const int* __restrict__ csr_col,
                                                           int n, int nperm) {
    int wave = (blockIdx.x * blockDim.x + threadIdx.x) >> 6;
    int lane = threadIdx.x & 63;
    int e = lane / 5;           // 12 for lanes 60..63
    int gl = lane - e * 5;
    int pidx = wave * 12 + e;
    bool inb = (e < 12) && (pidx < nperm);
    uint4 info = pinfo[inb ? pidx : 0];   // entry 0 is always valid -> safe base
    int s = (int)info.x;
    int len = inb ? (int)info.y : 0;
    int r = inb ? (int)info.z : -1;
    float dr = __uint_as_float(inb ? info.w : 0u);
    int maxlen = len;
#pragma unroll
    for (int o = 1; o < 64; o <<= 1) maxlen = max(maxlen, __shfl_xor(maxlen, o, 64));

    v2f h0 = {0.f,0.f}, h1 = {0.f,0.f}, h2 = {0.f,0.f}, h3 = {0.f,0.f};
    const uint4* cp = (const uint4*)(csr_col + s);  // s is a multiple of 4
    for (int base = 0; base < maxlen; base += 8) {
        GATHER8(cp, xs_in, gl, base, len)
    }
    if (r >= 0 && r < n) {
        uint4 us = xs_in[r * NV4 + gl];   // self term
        acc2p(us.x, h0); acc2p(us.y, h1); acc2p(us.z, h2); acc2p(us.w, h3);
        float d2 = dr * dr;
        uint4 o;
        o.x = pack_bf16_2(d2 * h0.x, d2 * h0.y);
        o.y = pack_bf16_2(d2 * h1.x, d2 * h1.y);
        o.z = pack_bf16_2(d2 * h2.x, d2 * h2.y);
        o.w = pack_bf16_2(d2 * h3.x, d2 * h3.y);
        xs_out[r * NV4 + gl] = o;
    }
}

// Hop 2 + bias + log_softmax: logits[r,:] = dis[r]*(y1[r,:]+sum_c y1[c,:]) + b.
// No GEMV: hop output IS the logits row. log_softmax over the 5-lane group
// via explicit 5-source __shfl max/sum (fixed order, all lanes identical).
__global__ __launch_bounds__(256, 8) void spmm_logits_kernel(const uint4* __restrict__ xs_in,
                                                             const uint4* __restrict__ pinfo,
                                                             const int* __restrict__ csr_col,
                                                             const float* __restrict__ b,
                                                             float* __restrict__ out,
                                                             int n, int nperm) {
    int wave = (blockIdx.x * blockDim.x + threadIdx.x) >> 6;
    int lane = threadIdx.x & 63;
    int e = lane / 5;
    int gl = lane - e * 5;
    int pidx = wave * 12 + e;
    bool inb = (e < 12) && (pidx < nperm);
    uint4 info = pinfo[inb ? pidx : 0];
    int s = (int)info.x;
    int len = inb ? (int)info.y : 0;
    int r = inb ? (int)info.z : -1;
    float dr = __uint_as_float(inb ? info.w : 0u);
    int maxlen = len;
#pragma unroll
    for (int o = 1; o < 64; o <<= 1) maxlen = max(maxlen, __shfl_xor(maxlen, o, 64));

    v2f h0 = {0.f,0.f}, h1 = {0.f,0.f}, h2 = {0.f,0.f}, h3 = {0.f,0.f};
    const uint4* cp = (const uint4*)(csr_col + s);
    for (int base = 0; base < maxlen; base += 8) {
        GATHER8(cp, xs_in, gl, base, len)
    }
    uint4 us = (r >= 0 && r < n) ? xs_in[r * NV4 + gl] : make_uint4(0u, 0u, 0u, 0u);
    acc2p(us.x, h0); acc2p(us.y, h1); acc2p(us.z, h2); acc2p(us.w, h3);

    // logits for classes 8gl..8gl+7 (dr = 0 for invalid lanes -> y = bias)
    const float4* b4 = (const float4*)b;
    float4 ba = b4[gl * 2], bb = b4[gl * 2 + 1];
    float y0 = dr * h0.x + ba.x, y1 = dr * h0.y + ba.y;
    float y2 = dr * h1.x + ba.z, y3 = dr * h1.y + ba.w;
    float y4 = dr * h2.x + bb.x, y5 = dr * h2.y + bb.y;
    float y6 = dr * h3.x + bb.z, y7 = dr * h3.y + bb.w;

    // group log_softmax: explicit 5-source shfl reduce (clamped for idle lanes)
    int gb = ((e < 12) ? e : 11) * 5;
    float mloc = fmaxf(fmaxf(fmaxf(y0, y1), fmaxf(y2, y3)),
                       fmaxf(fmaxf(y4, y5), fmaxf(y6, y7)));
    float M = mloc;
#pragma unroll
    for (int k = 0; k < 5; k++) M = fmaxf(M, __shfl(mloc, gb + k, 64));
    float sloc = __expf(y0 - M) + __expf(y1 - M) + __expf(y2 - M) + __expf(y3 - M) +
                 __expf(y4 - M) + __expf(y5 - M) + __expf(y6 - M) + __expf(y7 - M);
    float S = 0.f;
#pragma unroll
    for (int k = 0; k < 5; k++) S += __shfl(sloc, gb + k, 64);
    float lse = M + __logf(S);

    if (r >= 0 && r < n) {
        float4* op = (float4*)(out + (size_t)r * NCLS) + gl * 2;
        op[0] = make_float4(y0 - lse, y1 - lse, y2 - lse, y3 - lse);
        op[1] = make_float4(y4 - lse, y5 - lse, y6 - lse, y7 - lse);
    }
}

extern "C" void kernel_launch(void* const* d_in, const int* in_sizes, int n_in,
                              void* d_out, int out_size, void* d_ws, size_t ws_size,
                              hipStream_t stream) {
    const float* x  = (const float*)d_in[0];
    const int*   ei = (const int*)d_in[1];   // [2, E] flat: rows then cols (int32)
    const float* W  = (const float*)d_in[2]; // [64, 40]
    const float* b  = (const float*)d_in[3]; // [40]
    float* out = (float*)d_out;

    const int n = in_sizes[0] / D_FEAT;      // 100000
    const int e = in_sizes[1] / 2;           // 1600000
    const int nb = (n + BROWS - 1) / BROWS;  // 196

    const int* rows = ei;
    const int* cols = ei + e;

    // ws layout (int units, segments aligned):
    //   bucket_cursor | dis[n] | row_info[n] (uint2) | pinfo[nb*512] (uint4) |
    //   bins[nb*BINCAP] | csr_col[nb*CSRCAP] | y0 | y1       (~40 MB)
    size_t na = ((size_t)n + 256) & ~(size_t)255;
    size_t npm = (size_t)nb * BROWS;         // multiple of 512
    int*      bucket_cursor = (int*)d_ws;
    float*    dis           = (float*)(bucket_cursor + 256);
    uint2*    row_info      = (uint2*)(dis + na);
    uint4*    pinfo         = (uint4*)(row_info + na);
    unsigned* bins          = (unsigned*)(pinfo + npm);
    int*      csr_col       = (int*)(bins + (size_t)nb * BINCAP);
    unsigned* y0            = (unsigned*)(csr_col + (size_t)nb * CSRCAP);
    unsigned* y1            = y0 + (size_t)(n + 1) * NDW;

    const int BS = 256;

    init_kernel<<<1, 256, 0, stream>>>(bucket_cursor, y0, y1, n, nb);
    {
        int blocks = (e + BS * EPT - 1) / (BS * EPT);  // 782
        bin_edges_kernel<<<blocks, BS, 0, stream>>>(rows, cols, bucket_cursor, bins, e, nb);
    }
    build_csr_kernel<<<nb, 512, 0, stream>>>(bins, bucket_cursor, csr_col, row_info, dis,
                                             pinfo, n);
    {
        int nwv = (n + 1) / 2;                           // sort: 2 rows per wave
        int sortBlocks = (nwv * 64 + BS - 1) / BS;
        sort_rows_kernel<<<sortBlocks, BS, 0, stream>>>(csr_col, row_info, n);
    }
    {
        int blocks = (n + BS - 1) / BS;                  // 391, 1 row/thread
        xw_kernel<<<blocks, BS, 0, stream>>>(x, W, dis, y0, n);
    }

    int nperm = (int)npm;                    // nb*512 pinfo slots
    int nwaves = (nperm + 11) / 12;          // 12 rows per wave
    int blocks = (nwaves + 3) / 4;           // 4 waves per 256-thread block
    spmm_hop1_kernel<<<blocks, BS, 0, stream>>>((const uint4*)y0, (uint4*)y1, pinfo,
                                                csr_col, n, nperm);
    spmm_logits_kernel<<<blocks, BS, 0, stream>>>((const uint4*)y1, pinfo, csr_col,
                                                  b, out, n, nperm);
}

// Round 13
// 209.655 us; speedup vs baseline: 1.1161x; 1.1161x over previous
//
#include <hip/hip_runtime.h>
#include <math.h>

// SGC: K=2 hops of D^-1/2 (A+I) D^-1/2, then x@W+b, then log_softmax.
// N=100000, D=64, C=40, E=1600000.
//
// R21: restore R18's proven spmm/bin_edges config, drop the row sort.
//  - spmm kernels back to launch_bounds(256,5) + dual accumulator banks
//    (R19/R20's (256,8) cap=64 VGPR re-serialized the 16-load pipeline:
//    8x uint4 payload + cv + addrs > 64 -> R12-era failure mode).
//  - bin_edges back to EPT=25 (EPT=8 tripled global cursor atomics).
//  - sort_rows DELETED: it existed only for bit-identical replay output;
//    correctness is absmax<0.0769 vs reference, and atomic-order summation
//    moves bf16 results by ~ulp (~0.008). row_info is dead -> removed.
//
// Carried: XW-first pipeline (R16-R18), init_kernel instead of memsets
// (R18), 5-lane x uint4 gathers (12 rows/wave), pinfo, guard region,
// degree-grouped scheduling, pk_add accumulate.

#define D_FEAT 64
#define NCLS 40
#define NDW 20          // dwords per 40-bf16 row
#define NV4 5           // uint4 per row
#define BROWS 512       // rows per bucket
#define BROWS_LOG 9
#define BINCAP 10240    // per-bucket edge capacity (mean 8192, sd ~90)
#define CSRCAP 12288    // per-bucket csr capacity (max padded 11776 + 512 guard)
#define EPT 25          // edges per thread in bin_edges (250 blocks)

typedef float v2f __attribute__((ext_vector_type(2)));

__device__ __forceinline__ unsigned pack_bf16_2(float lo, float hi) {
    unsigned ulo = __float_as_uint(lo);
    unsigned uhi = __float_as_uint(hi);
    ulo = (ulo + 0x7fffu + ((ulo >> 16) & 1u)) >> 16;           // RNE
    uhi = (uhi + 0x7fffu + ((uhi >> 16) & 1u)) & 0xffff0000u;   // RNE
    return uhi | ulo;
}

// packed-accumulate one dword (2 bf16 features) into a float2 accumulator
__device__ __forceinline__ void acc2p(unsigned u, v2f& a) {
    v2f v;
    v.x = __uint_as_float(u << 16);
    v.y = __uint_as_float(u & 0xffff0000u);
    a += v;   // <2 x float> fadd -> v_pk_add_f32
}

// Zero bucket_cursor + the dummy row n of y0/y1 (guard-gather target).
__global__ void init_kernel(int* __restrict__ bucket_cursor,
                            unsigned* __restrict__ y0, unsigned* __restrict__ y1,
                            int n, int nb) {
    int i = threadIdx.x;
    if (i < nb) bucket_cursor[i] = 0;
    if (i < NDW) {
        y0[(size_t)n * NDW + i] = 0u;
        y1[(size_t)n * NDW + i] = 0u;
    }
}

// Bin edges into per-bucket regions. Packed entry: (row&511)<<17 | col.
// (Requires n <= 131072 so col fits 17 bits; n = 100000 here.)
__global__ __launch_bounds__(256) void bin_edges_kernel(const int* __restrict__ rows,
                                                        const int* __restrict__ cols,
                                                        int* __restrict__ bucket_cursor,
                                                        unsigned* __restrict__ bins,
                                                        int e, int nb) {
    __shared__ int cnt[512];
    for (int i = threadIdx.x; i < nb; i += 256) cnt[i] = 0;
    __syncthreads();
    int base = blockIdx.x * (256 * EPT) + threadIdx.x;
    int rr[EPT], cc[EPT];
#pragma unroll
    for (int k = 0; k < EPT; k++) {
        int idx = base + k * 256;
        if (idx < e) { rr[k] = rows[idx]; cc[k] = cols[idx]; }
        else { rr[k] = -1; cc[k] = 0; }
    }
#pragma unroll
    for (int k = 0; k < EPT; k++)
        if (rr[k] >= 0) atomicAdd(&cnt[rr[k] >> BROWS_LOG], 1);
    __syncthreads();
    for (int i = threadIdx.x; i < nb; i += 256) {
        int c = cnt[i];
        cnt[i] = (c > 0) ? atomicAdd(&bucket_cursor[i], c) : 0;  // global base
    }
    __syncthreads();
#pragma unroll
    for (int k = 0; k < EPT; k++) {
        if (rr[k] >= 0) {
            int b = rr[k] >> BROWS_LOG;
            int pos = atomicAdd(&cnt[b], 1);  // absolute pos within bucket
            bins[(size_t)b * BINCAP + pos] =
                ((unsigned)(rr[k] & (BROWS - 1)) << 17) | (unsigned)cc[k];
        }
    }
}

// One 512-thread block per bucket, all staged in LDS. Emits dummy-padded CSR
// (unsorted; summation order nondeterministic at ~ulp level) + 512-entry
// guard (value n) + dis + pinfo (degree-grouped wave schedule).
__global__ __launch_bounds__(512) void build_csr_kernel(const unsigned* __restrict__ bins,
                                                        const int* __restrict__ bucket_cursor,
                                                        int* __restrict__ csr_col,
                                                        float* __restrict__ dis,
                                                        uint4* __restrict__ pinfo, int n) {
    __shared__ int cnt[512];
    __shared__ int sm[512];
    __shared__ int cur[512];
    __shared__ int lcsr[CSRCAP];  // 48 KB; total static LDS = 54 KB
    int b = blockIdx.x;
    int tid = threadIdx.x;
    int m = bucket_cursor[b];
    cnt[tid] = 0;
    __syncthreads();
    const unsigned* bp = bins + (size_t)b * BINCAP;
    for (int i = tid; i < m; i += 512) atomicAdd(&cnt[bp[i] >> 17], 1);
    __syncthreads();
    int c = cnt[tid];
    int padded = (c + 3) & ~3;
    int r = b * BROWS + tid;
    float dv = rsqrtf(1.0f + (float)c);
    if (r < n) dis[r] = dv;
    sm[tid] = padded;
    __syncthreads();
    for (int off = 1; off < 512; off <<= 1) {
        int t = (tid >= off) ? sm[tid - off] : 0;
        __syncthreads();
        sm[tid] += t;
        __syncthreads();
    }
    int off0 = sm[tid] - padded;  // exclusive scan
    cur[tid] = off0;
    __syncthreads();
    for (int i = tid; i < m; i += 512) {
        unsigned u = bp[i];
        int pos = atomicAdd(&cur[u >> 17], 1);
        lcsr[pos] = (int)(u & 0x1FFFFu);
    }
    __syncthreads();
    // dummy-pad own row's tail (pad slots gather zero row n in SpMM)
    if (r < n) {
        for (int j = c; j < padded; j++) lcsr[off0 + j] = n;
    }
    __syncthreads();
    int tot = sm[511];  // total padded slots (multiple of 4)
    int4* cp4 = (int4*)(csr_col + (size_t)b * CSRCAP);
    const int4* l4 = (const int4*)lcsr;
    for (int i = tid; i < (tot >> 2); i += 512) cp4[i] = l4[i];
    // guard region: SpMM reads csr up to ~256 ints past a row's end; fill 512
    // entries of value n past tot (row n of y0/y1 is zeros).
    {
        int g = tot + tid;
        if (g < CSRCAP) csr_col[(size_t)b * CSRCAP + g] = n;
    }

    // ---- degree-grouped pinfo: counting sort of bucket rows by padded len --
    // (rank order within a bin is nondeterministic, but output is per-row
    //  independent of wave assignment.)
    __syncthreads();
    if (tid < 64) cnt[tid] = 0;
    __syncthreads();
    int bin = min(padded >> 2, 63);
    if (r < n) atomicAdd(&cnt[bin], 1);
    __syncthreads();
    if (tid < 64) sm[tid] = cnt[tid];
    __syncthreads();
    for (int off = 1; off < 64; off <<= 1) {
        int t = (tid >= off && tid < 64) ? sm[tid - off] : 0;
        __syncthreads();
        if (tid < 64) sm[tid] += t;
        __syncthreads();
    }
    if (tid < 64) cur[tid] = sm[tid] - cnt[tid];  // exclusive bin base
    __syncthreads();
    if (r < n) {
        int rank = atomicAdd(&cur[bin], 1);
        pinfo[b * BROWS + rank] = make_uint4((unsigned)(b * CSRCAP + off0),
                                             (unsigned)padded, (unsigned)r,
                                             __float_as_uint(dv));
    } else {
        // tid >= valid-count exactly when r >= n
        pinfo[b * BROWS + tid] = make_uint4(0u, 0u, 0xFFFFFFFFu, 0u);
    }
}

// Y0[r,:] = bf16( dis[r] * (X[r,:] @ W) ), 40 bf16 packed into 20 dwords.
// 1 row per thread; W read via wave-uniform global addresses (scalar K$
// loads -- no LDS, no barrier); X streamed float4; uint4 stores.
__global__ __launch_bounds__(256) void xw_kernel(const float* __restrict__ x,
                                                 const float* __restrict__ W,
                                                 const float* __restrict__ dis,
                                                 unsigned* __restrict__ y0, int n) {
    int r = blockIdx.x * 256 + threadIdx.x;
    if (r >= n) return;
    float acc[NCLS];
#pragma unroll
    for (int c = 0; c < NCLS; c++) acc[c] = 0.f;
    const float4* xp = (const float4*)(x + (size_t)r * D_FEAT);
#pragma unroll 4
    for (int dg = 0; dg < 16; dg++) {
        float4 xa = xp[dg];
#pragma unroll
        for (int j = 0; j < 4; j++) {
            float a = (j == 0) ? xa.x : (j == 1) ? xa.y : (j == 2) ? xa.z : xa.w;
            int d = dg * 4 + j;
#pragma unroll
            for (int c4 = 0; c4 < 10; c4++) {
                float4 wv = *(const float4*)(W + d * NCLS + c4 * 4);  // uniform
                acc[c4 * 4 + 0] += a * wv.x;
                acc[c4 * 4 + 1] += a * wv.y;
                acc[c4 * 4 + 2] += a * wv.z;
                acc[c4 * 4 + 3] += a * wv.w;
            }
        }
    }
    float s = dis[r];
    uint4* p = (uint4*)(y0 + (size_t)r * NDW);
#pragma unroll
    for (int q = 0; q < NV4; q++) {
        uint4 o;
        o.x = pack_bf16_2(s * acc[8 * q + 0], s * acc[8 * q + 1]);
        o.y = pack_bf16_2(s * acc[8 * q + 2], s * acc[8 * q + 3]);
        o.z = pack_bf16_2(s * acc[8 * q + 4], s * acc[8 * q + 5]);
        o.w = pack_bf16_2(s * acc[8 * q + 6], s * acc[8 * q + 7]);
        p[q] = o;
    }
}

// One gather iteration: 8 UNCONDITIONAL uint4 row-gathers (5 lanes per row,
// 12 rows per wave) + sched_barrier, then accumulates predicated per 4-slot
// group. Dual accumulator banks (A/B) halve the pk_add dependency chain;
// launch_bounds(256,5) leaves ~102 VGPR so all 8 loads stay in flight.
#define ACCA(u) acc2p(u.x, h0A); acc2p(u.y, h1A); acc2p(u.z, h2A); acc2p(u.w, h3A);
#define ACCB(u) acc2p(u.x, h0B); acc2p(u.y, h1B); acc2p(u.z, h2B); acc2p(u.w, h3B);
#define GATHER8(cp, xs4, gl, base, len)                                     \
    uint4 cv0 = cp[(base >> 2)], cv1 = cp[(base >> 2) + 1];                 \
    uint4 u0 = xs4[cv0.x * NV4 + gl], u1 = xs4[cv0.y * NV4 + gl];           \
    uint4 u2 = xs4[cv0.z * NV4 + gl], u3 = xs4[cv0.w * NV4 + gl];           \
    uint4 u4 = xs4[cv1.x * NV4 + gl], u5 = xs4[cv1.y * NV4 + gl];           \
    uint4 u6 = xs4[cv1.z * NV4 + gl], u7 = xs4[cv1.w * NV4 + gl];           \
    __builtin_amdgcn_sched_barrier(0);                                      \
    if (base < len)     { ACCA(u0) ACCA(u1) ACCA(u2) ACCA(u3) }             \
    if (base + 4 < len) { ACCB(u4) ACCB(u5) ACCB(u6) ACCB(u7) }

// Hop 1: y1[r,:] = bf16( dis[r]^2 * ( y0[r,:] + sum_c y0[c,:] ) ).
// Wave: 12 rows from pinfo[12w..12w+11]; 5-lane group per row; lane gl holds
// feats 8gl..8gl+7 (uint4). Lanes 60..63 idle.
__global__ __launch_bounds__(256, 5) void spmm_hop1_kernel(const uint4* __restrict__ xs_in,
                                                           uint4* __restrict__ xs_out,
                                                           const uint4* __restrict__ pinfo,
                                                           const int* __restrict__ csr_col,
                                                           int n, int nperm) {
    int wave = (blockIdx.x * blockDim.x + threadIdx.x) >> 6;
    int lane = threadIdx.x & 63;
    int e = lane / 5;           // 12 for lanes 60..63
    int gl = lane - e * 5;
    int pidx = wave * 12 + e;
    bool inb = (e < 12) && (pidx < nperm);
    uint4 info = pinfo[inb ? pidx : 0];   // entry 0 is always valid -> safe base
    int s = (int)info.x;
    int len = inb ? (int)info.y : 0;
    int r = inb ? (int)info.z : -1;
    float dr = __uint_as_float(inb ? info.w : 0u);
    int maxlen = len;
#pragma unroll
    for (int o = 1; o < 64; o <<= 1) maxlen = max(maxlen, __shfl_xor(maxlen, o, 64));

    v2f h0A = {0.f,0.f}, h1A = {0.f,0.f}, h2A = {0.f,0.f}, h3A = {0.f,0.f};
    v2f h0B = {0.f,0.f}, h1B = {0.f,0.f}, h2B = {0.f,0.f}, h3B = {0.f,0.f};
    const uint4* cp = (const uint4*)(csr_col + s);  // s is a multiple of 4
    for (int base = 0; base < maxlen; base += 8) {
        GATHER8(cp, xs_in, gl, base, len)
    }
    if (r >= 0 && r < n) {
        v2f h0 = h0A + h0B, h1 = h1A + h1B, h2 = h2A + h2B, h3 = h3A + h3B;
        uint4 us = xs_in[r * NV4 + gl];   // self term
        acc2p(us.x, h0); acc2p(us.y, h1); acc2p(us.z, h2); acc2p(us.w, h3);
        float d2 = dr * dr;
        uint4 o;
        o.x = pack_bf16_2(d2 * h0.x, d2 * h0.y);
        o.y = pack_bf16_2(d2 * h1.x, d2 * h1.y);
        o.z = pack_bf16_2(d2 * h2.x, d2 * h2.y);
        o.w = pack_bf16_2(d2 * h3.x, d2 * h3.y);
        xs_out[r * NV4 + gl] = o;
    }
}

// Hop 2 + bias + log_softmax: logits[r,:] = dis[r]*(y1[r,:]+sum_c y1[c,:]) + b.
// No GEMV: hop output IS the logits row. log_softmax over the 5-lane group
// via explicit 5-source __shfl max/sum (fixed order, all lanes identical).
__global__ __launch_bounds__(256, 5) void spmm_logits_kernel(const uint4* __restrict__ xs_in,
                                                             const uint4* __restrict__ pinfo,
                                                             const int* __restrict__ csr_col,
                                                             const float* __restrict__ b,
                                                             float* __restrict__ out,
                                                             int n, int nperm) {
    int wave = (blockIdx.x * blockDim.x + threadIdx.x) >> 6;
    int lane = threadIdx.x & 63;
    int e = lane / 5;
    int gl = lane - e * 5;
    int pidx = wave * 12 + e;
    bool inb = (e < 12) && (pidx < nperm);
    uint4 info = pinfo[inb ? pidx : 0];
    int s = (int)info.x;
    int len = inb ? (int)info.y : 0;
    int r = inb ? (int)info.z : -1;
    float dr = __uint_as_float(inb ? info.w : 0u);
    int maxlen = len;
#pragma unroll
    for (int o = 1; o < 64; o <<= 1) maxlen = max(maxlen, __shfl_xor(maxlen, o, 64));

    v2f h0A = {0.f,0.f}, h1A = {0.f,0.f}, h2A = {0.f,0.f}, h3A = {0.f,0.f};
    v2f h0B = {0.f,0.f}, h1B = {0.f,0.f}, h2B = {0.f,0.f}, h3B = {0.f,0.f};
    const uint4* cp = (const uint4*)(csr_col + s);
    for (int base = 0; base < maxlen; base += 8) {
        GATHER8(cp, xs_in, gl, base, len)
    }
    v2f h0 = h0A + h0B, h1 = h1A + h1B, h2 = h2A + h2B, h3 = h3A + h3B;
    uint4 us = (r >= 0 && r < n) ? xs_in[r * NV4 + gl] : make_uint4(0u, 0u, 0u, 0u);
    acc2p(us.x, h0); acc2p(us.y, h1); acc2p(us.z, h2); acc2p(us.w, h3);

    // logits for classes 8gl..8gl+7 (dr = 0 for invalid lanes -> y = bias)
    const float4* b4 = (const float4*)b;
    float4 ba = b4[gl * 2], bb = b4[gl * 2 + 1];
    float y0 = dr * h0.x + ba.x, y1 = dr * h0.y + ba.y;
    float y2 = dr * h1.x + ba.z, y3 = dr * h1.y + ba.w;
    float y4 = dr * h2.x + bb.x, y5 = dr * h2.y + bb.y;
    float y6 = dr * h3.x + bb.z, y7 = dr * h3.y + bb.w;

    // group log_softmax: explicit 5-source shfl reduce (clamped for idle lanes)
    int gb = ((e < 12) ? e : 11) * 5;
    float mloc = fmaxf(fmaxf(fmaxf(y0, y1), fmaxf(y2, y3)),
                       fmaxf(fmaxf(y4, y5), fmaxf(y6, y7)));
    float M = mloc;
#pragma unroll
    for (int k = 0; k < 5; k++) M = fmaxf(M, __shfl(mloc, gb + k, 64));
    float sloc = __expf(y0 - M) + __expf(y1 - M) + __expf(y2 - M) + __expf(y3 - M) +
                 __expf(y4 - M) + __expf(y5 - M) + __expf(y6 - M) + __expf(y7 - M);
    float S = 0.f;
#pragma unroll
    for (int k = 0; k < 5; k++) S += __shfl(sloc, gb + k, 64);
    float lse = M + __logf(S);

    if (r >= 0 && r < n) {
        float4* op = (float4*)(out + (size_t)r * NCLS) + gl * 2;
        op[0] = make_float4(y0 - lse, y1 - lse, y2 - lse, y3 - lse);
        op[1] = make_float4(y4 - lse, y5 - lse, y6 - lse, y7 - lse);
    }
}

extern "C" void kernel_launch(void* const* d_in, const int* in_sizes, int n_in,
                              void* d_out, int out_size, void* d_ws, size_t ws_size,
                              hipStream_t stream) {
    const float* x  = (const float*)d_in[0];
    const int*   ei = (const int*)d_in[1];   // [2, E] flat: rows then cols (int32)
    const float* W  = (const float*)d_in[2]; // [64, 40]
    const float* b  = (const float*)d_in[3]; // [40]
    float* out = (float*)d_out;

    const int n = in_sizes[0] / D_FEAT;      // 100000
    const int e = in_sizes[1] / 2;           // 1600000
    const int nb = (n + BROWS - 1) / BROWS;  // 196

    const int* rows = ei;
    const int* cols = ei + e;

    // ws layout (int units, segments aligned):
    //   bucket_cursor | dis[n] | pinfo[nb*512] (uint4) |
    //   bins[nb*BINCAP] | csr_col[nb*CSRCAP] | y0 | y1       (~39 MB)
    size_t na = ((size_t)n + 256) & ~(size_t)255;
    size_t npm = (size_t)nb * BROWS;         // multiple of 512
    int*      bucket_cursor = (int*)d_ws;
    float*    dis           = (float*)(bucket_cursor + 256);
    uint4*    pinfo         = (uint4*)(dis + na);
    unsigned* bins          = (unsigned*)(pinfo + npm);
    int*      csr_col       = (int*)(bins + (size_t)nb * BINCAP);
    unsigned* y0            = (unsigned*)(csr_col + (size_t)nb * CSRCAP);
    unsigned* y1            = y0 + (size_t)(n + 1) * NDW;

    const int BS = 256;

    init_kernel<<<1, 256, 0, stream>>>(bucket_cursor, y0, y1, n, nb);
    {
        int blocks = (e + BS * EPT - 1) / (BS * EPT);  // 250
        bin_edges_kernel<<<blocks, BS, 0, stream>>>(rows, cols, bucket_cursor, bins, e, nb);
    }
    build_csr_kernel<<<nb, 512, 0, stream>>>(bins, bucket_cursor, csr_col, dis,
                                             pinfo, n);
    {
        int blocks = (n + BS - 1) / BS;                  // 391, 1 row/thread
        xw_kernel<<<blocks, BS, 0, stream>>>(x, W, dis, y0, n);
    }

    int nperm = (int)npm;                    // nb*512 pinfo slots
    int nwaves = (nperm + 11) / 12;          // 12 rows per wave
    int blocks = (nwaves + 3) / 4;           // 4 waves per 256-thread block
    spmm_hop1_kernel<<<blocks, BS, 0, stream>>>((const uint4*)y0, (uint4*)y1, pinfo,
                                                csr_col, n, nperm);
    spmm_logits_kernel<<<blocks, BS, 0, stream>>>((const uint4*)y1, pinfo, csr_col,
                                                  b, out, n, nperm);
}